// Round 4
// baseline (154.925 us; speedup 1.0000x reference)
//
#include <hip/hip_runtime.h>
#include <hip/hip_cooperative_groups.h>

namespace cg = cooperative_groups;

// out[j] = sum(x) for all j — single cooperative kernel.
// Phase 1: grid-stride float4 partial sums -> partials[] in ws.
// grid.sync()
// Phase 2: each block re-reduces the 2048 partials (fixed deterministic
//          tree, L2/L3-resident) then broadcast-fills its slice with
//          plain 16B stores.

#define NBLK 2048
#define NTHR 256

typedef float vfloat4 __attribute__((ext_vector_type(4)));

__global__ __launch_bounds__(NTHR, 8) void fused_sum_fill_kernel(
    const vfloat4* __restrict__ x4, const float* __restrict__ x,
    float* __restrict__ partials,
    vfloat4* __restrict__ out4, float* __restrict__ out,
    int n4, int n)
{
    cg::grid_group grid = cg::this_grid();

    __shared__ float smem[NTHR / 64];
    __shared__ float total_sh;

    int tid    = blockIdx.x * blockDim.x + threadIdx.x;
    int stride = gridDim.x * blockDim.x;
    int lane   = threadIdx.x & 63;
    int wid    = threadIdx.x >> 6;

    // ---- Phase 1: per-block partial sum ----
    float s = 0.0f;
    for (int i = tid; i < n4; i += stride) {
        vfloat4 v = x4[i];
        s += (v.x + v.y) + (v.z + v.w);
    }
    int tail_start = n4 * 4;
    int tail_n = n - tail_start;
    if (tid < tail_n) s += x[tail_start + tid];

    #pragma unroll
    for (int off = 32; off > 0; off >>= 1)
        s += __shfl_down(s, off, 64);

    if (lane == 0) smem[wid] = s;
    __syncthreads();
    if (threadIdx.x == 0) {
        float t = 0.0f;
        #pragma unroll
        for (int w = 0; w < NTHR / 64; ++w) t += smem[w];
        partials[blockIdx.x] = t;
    }

    grid.sync();

    // ---- Phase 2: every block re-reduces the NBLK partials ----
    // Fixed tree, identical in every block -> bit-identical total.
    const vfloat4* p4 = (const vfloat4*)partials;
    float r = 0.0f;
    #pragma unroll
    for (int k = 0; k < NBLK / 4 / NTHR; ++k) {
        vfloat4 v = p4[threadIdx.x + k * NTHR];
        r += (v.x + v.y) + (v.z + v.w);
    }
    #pragma unroll
    for (int off = 32; off > 0; off >>= 1)
        r += __shfl_down(r, off, 64);

    if (lane == 0) smem[wid] = r;
    __syncthreads();
    if (threadIdx.x == 0) {
        float t = 0.0f;
        #pragma unroll
        for (int w = 0; w < NTHR / 64; ++w) t += smem[w];
        total_sh = t;
    }
    __syncthreads();

    float t = total_sh;
    vfloat4 v = { t, t, t, t };

    for (int i = tid; i < n4; i += stride)
        out4[i] = v;
    if (tid < tail_n) out[tail_start + tid] = t;
}

extern "C" void kernel_launch(void* const* d_in, const int* in_sizes, int n_in,
                              void* d_out, int out_size, void* d_ws, size_t ws_size,
                              hipStream_t stream)
{
    const float*   x    = (const float*)d_in[0];
    const vfloat4* x4   = (const vfloat4*)d_in[0];
    float*         out  = (float*)d_out;
    vfloat4*       out4 = (vfloat4*)d_out;

    int n  = in_sizes[0];
    int n4 = n / 4;

    float* partials = (float*)d_ws;  // NBLK floats

    void* args[] = { (void*)&x4, (void*)&x, (void*)&partials,
                     (void*)&out4, (void*)&out, (void*)&n4, (void*)&n };
    hipLaunchCooperativeKernel((const void*)fused_sum_fill_kernel,
                               dim3(NBLK), dim3(NTHR), args, 0, stream);
}

// Round 5
// 50.021 us; speedup vs baseline: 3.0972x; 3.0972x over previous
//
#include <hip/hip_runtime.h>

// out[j] = sum(x) for all j.
// Kernel 1: per-block partial sums (float4 vectorized, grid-stride) -> ws.
// Kernel 2: each block re-reduces the 2048 partials (fixed deterministic
//           tree, L2/L3-resident, ~8 KB) then broadcast-fills its slice
//           of out with plain 16B stores.

#define NBLK 2048
#define NTHR 256

typedef float vfloat4 __attribute__((ext_vector_type(4)));

__global__ __launch_bounds__(NTHR) void reduce_partial_kernel(
    const vfloat4* __restrict__ x4, const float* __restrict__ x,
    float* __restrict__ partials, int n4, int n)
{
    int tid    = blockIdx.x * blockDim.x + threadIdx.x;
    int stride = gridDim.x * blockDim.x;

    float s = 0.0f;
    for (int i = tid; i < n4; i += stride) {
        vfloat4 v = x4[i];
        s += (v.x + v.y) + (v.z + v.w);
    }
    // scalar tail (n not divisible by 4)
    int tail_start = n4 * 4;
    int tail_n = n - tail_start;
    if (tid < tail_n) s += x[tail_start + tid];

    #pragma unroll
    for (int off = 32; off > 0; off >>= 1)
        s += __shfl_down(s, off, 64);

    __shared__ float smem[NTHR / 64];
    int lane = threadIdx.x & 63;
    int wid  = threadIdx.x >> 6;
    if (lane == 0) smem[wid] = s;
    __syncthreads();
    if (threadIdx.x == 0) {
        float t = 0.0f;
        #pragma unroll
        for (int w = 0; w < NTHR / 64; ++w) t += smem[w];
        partials[blockIdx.x] = t;
    }
}

__global__ __launch_bounds__(NTHR) void fill_total_kernel(
    vfloat4* __restrict__ out4, float* __restrict__ out,
    const float* __restrict__ partials, int n4, int n)
{
    // Per-block re-reduction of the NBLK partials (identical fixed tree in
    // every block -> bit-identical total everywhere). 8 KB, L2-resident.
    const vfloat4* p4 = (const vfloat4*)partials;
    float r = 0.0f;
    #pragma unroll
    for (int k = 0; k < NBLK / 4 / NTHR; ++k) {
        vfloat4 v = p4[threadIdx.x + k * NTHR];
        r += (v.x + v.y) + (v.z + v.w);
    }
    #pragma unroll
    for (int off = 32; off > 0; off >>= 1)
        r += __shfl_down(r, off, 64);

    __shared__ float smem[NTHR / 64];
    __shared__ float total_sh;
    int lane = threadIdx.x & 63;
    int wid  = threadIdx.x >> 6;
    if (lane == 0) smem[wid] = r;
    __syncthreads();
    if (threadIdx.x == 0) {
        float t = 0.0f;
        #pragma unroll
        for (int w = 0; w < NTHR / 64; ++w) t += smem[w];
        total_sh = t;
    }
    __syncthreads();

    float t = total_sh;
    vfloat4 v = { t, t, t, t };

    int tid    = blockIdx.x * blockDim.x + threadIdx.x;
    int stride = gridDim.x * blockDim.x;
    for (int i = tid; i < n4; i += stride)
        out4[i] = v;

    int tail_start = n4 * 4;
    int tail_n = n - tail_start;
    if (tid < tail_n) out[tail_start + tid] = t;
}

extern "C" void kernel_launch(void* const* d_in, const int* in_sizes, int n_in,
                              void* d_out, int out_size, void* d_ws, size_t ws_size,
                              hipStream_t stream)
{
    const float*   x    = (const float*)d_in[0];
    const vfloat4* x4   = (const vfloat4*)d_in[0];
    float*         out  = (float*)d_out;
    vfloat4*       out4 = (vfloat4*)d_out;

    int n  = in_sizes[0];
    int n4 = n / 4;

    float* partials = (float*)d_ws;  // NBLK floats

    reduce_partial_kernel<<<NBLK, NTHR, 0, stream>>>(x4, x, partials, n4, n);
    fill_total_kernel<<<NBLK, NTHR, 0, stream>>>(out4, out, partials, n4, out_size);
}